// Round 4
// baseline (1089.595 us; speedup 1.0000x reference)
//
#include <hip/hip_runtime.h>
#include <math.h>

// PhyloNeighbours: per-filter (16) kNN (k=8) over 2000 features, 512-dim coords.
// v4: approx kernel restructured — register-double-buffered staging (12 loads
// in flight, prefetch kc+1 under MFMA of kc) and a 4-wave float4 scan over an
// XOR-swizzled score tile. Candidate set provably identical to v3 (pairwise
// j-split partial top-10s merged lex-exact). Refine/select/gather unchanged
// (validated bit-exact vs numpy across rounds 1-3).
//
// Memory plan:
//   d_out: phase 1 holds cbt[f][2048][512] bf16 (32 MB); phase 2 holds
//          ct[f][2000][512] fp32 (exactly out_size floats); final gather output.
//   d_ws : sq (128 KB) + cand (1.28 MB) + dval (1.28 MB) + fidx (1 MB) ~= 3.7 MB.

#define F_TOT 2000
#define CF    16
#define KDIM  512
#define NB_K  8
#define IPAD  2048
#define NCAND 10

typedef __attribute__((ext_vector_type(8))) short bf16x8;
typedef __attribute__((ext_vector_type(4))) float f32x4;

__device__ inline unsigned short f2bf(float x) {
  unsigned int u = __float_as_uint(x);
  return (unsigned short)((u + 0x7fffu + ((u >> 16) & 1u)) >> 16);
}

// ---------------------------------------------------------------- k1: sq (fp64)
// VALIDATED rounds 1-3 — do not change arithmetic.
__global__ __launch_bounds__(256) void sq_kernel(const float* __restrict__ coords,
                                                 float* __restrict__ sq_out) {
  int i = blockIdx.x;
  int t = threadIdx.x;
  int f = t & 15;
  int cg = t >> 4;
  const float* base = coords + (size_t)i * CF + f;
  double s = 0.0;
  for (int c = cg * 32; c < cg * 32 + 32; ++c) {
    float v = base[(size_t)c * (F_TOT * CF)];
    s += (double)v * (double)v;
  }
  __shared__ double red[256];
  red[t] = s;
  __syncthreads();
  if (cg == 0) {
    double tot = 0.0;
#pragma unroll
    for (int g = 0; g < 16; ++g) tot += red[g * 16 + f];
    sq_out[i * CF + f] = (float)tot;
  }
}

// ------------------------------------------- k2: coords -> cbt[f][i pad2048][c] bf16
__global__ __launch_bounds__(256) void cvt_bf16_kernel(const float* __restrict__ coords,
                                                       unsigned short* __restrict__ cbt) {
  __shared__ float lds[32 * 257];
  const int i0 = blockIdx.x * 16;    // 0..2032
  const int c0 = blockIdx.y * 32;
  const int t = threadIdx.x;
  const int io = t >> 4, f = t & 15;
  const int iclamp = min(i0 + io, F_TOT - 1);
  for (int cc = 0; cc < 32; ++cc)
    lds[cc * 257 + t] = coords[(size_t)(c0 + cc) * (F_TOT * CF) + iclamp * CF + f];
  __syncthreads();
  size_t obase = ((size_t)f * IPAD + (i0 + io)) * KDIM + c0;
#pragma unroll
  for (int cc = 0; cc < 32; cc += 4) {
    unsigned int lo = (unsigned int)f2bf(lds[(cc + 0) * 257 + t]) |
                      ((unsigned int)f2bf(lds[(cc + 1) * 257 + t]) << 16);
    unsigned int hi = (unsigned int)f2bf(lds[(cc + 2) * 257 + t]) |
                      ((unsigned int)f2bf(lds[(cc + 3) * 257 + t]) << 16);
    *(uint2*)(cbt + obase + cc) = make_uint2(lo, hi);
  }
}

// ------------------------------------------- k4: coords -> ct[f][i 2000][c] fp32
__global__ __launch_bounds__(256) void cvt_f32t_kernel(const float* __restrict__ coords,
                                                       float* __restrict__ ct) {
  __shared__ float lds[32 * 257];
  const int i0 = blockIdx.x * 16;    // 0..1984 (125 tiles exact)
  const int c0 = blockIdx.y * 32;
  const int t = threadIdx.x;
  const int io = t >> 4;
  for (int cc = 0; cc < 32; ++cc)
    lds[cc * 257 + t] = coords[(size_t)(c0 + cc) * (F_TOT * CF) + i0 * CF + t];
  __syncthreads();
  const int f = t & 15;
  size_t obase = ((size_t)f * F_TOT + (i0 + io)) * KDIM + c0;
#pragma unroll
  for (int cc = 0; cc < 32; cc += 4) {
    float4 v = make_float4(lds[(cc + 0) * 257 + t], lds[(cc + 1) * 257 + t],
                           lds[(cc + 2) * 257 + t], lds[(cc + 3) * 257 + t]);
    *(float4*)(ct + obase + cc) = v;
  }
}

// ------------------------------------------- k3: bf16 MFMA approx + top-10 cand
// grid 256: f = bx&15, i-tile(128) = bx>>4. Each block scans ALL 2000 j.
// Staging: 12 uint4 register prefetch of kc+1 issued before MFMA of kc.
// Scan: 256 threads; thread pair (ii, ii+128) splits each row's j range;
// partial top-10s merged lex-exact at the end (== global top-10 of v3).
__global__ __launch_bounds__(256, 1) void approx_kernel(const unsigned short* __restrict__ cbt,
                                                        const float* __restrict__ sq,
                                                        int* __restrict__ cand) {
  const int bx = blockIdx.x;
  const int f = bx & 15;
  const int it = bx >> 4;
  const int ibase = it * 128;

  const int t = threadIdx.x;
  const int lane = t & 63;
  const int w = t >> 6;
  const int wi = w & 1, wj = w >> 1;
  const int lrow = lane & 15, lq = lane >> 4;

  __shared__ char smem[66560];
  unsigned short* Al = (unsigned short*)smem;             // [128][72] bf16
  unsigned short* Bl = (unsigned short*)(smem + 18432);   // [256][72] bf16
  float* Dl = (float*)smem;                               // [128][128] f32 swizzled (alias)
  float* sqj = (float*)(smem + 65536);                    // [256]

  const unsigned short* abase_g = cbt + ((size_t)f * IPAD + ibase) * KDIM;

  // scan identity: row ii, j-half (64 j per phase-slab of 128)
  const int ii = t & 127;
  const int half = t >> 7;
  const bool rowok = (ibase + ii < F_TOT);

  float bv[NCAND]; int bi[NCAND];
#pragma unroll
  for (int k = 0; k < NCAND; ++k) { bv[k] = __builtin_inff(); bi[k] = 0x7fffffff; }
  float sqi = rowok ? sq[(ibase + ii) * CF + f] : 0.0f;

  int aoff[4], boff2[8];
#pragma unroll
  for (int mi = 0; mi < 4; ++mi) aoff[mi] = (wi * 64 + mi * 16 + lrow) * 72 + lq * 8;
#pragma unroll
  for (int nj = 0; nj < 8; ++nj) boff2[nj] = (wj * 128 + nj * 16 + lrow) * 72 + lq * 8;

  // staging slot geometry (compile-time per thread)
  int rA[4], sA[4], rB[8], sB[8];
#pragma unroll
  for (int p = 0; p < 4; ++p) { int idx = t + p * 256; rA[p] = idx >> 3; sA[p] = idx & 7; }
#pragma unroll
  for (int p = 0; p < 8; ++p) { int idx = t + p * 256; rB[p] = idx >> 3; sB[p] = idx & 7; }
  uint4 rg[12];

  for (int js = 0; js < 8; ++js) {
    const int jbase = js * 256;
    __syncthreads();   // previous js's scan (Dl/sqj readers) done
    { int jg = jbase + t; sqj[t] = (jg < F_TOT) ? sq[jg * CF + f] : 0.0f; }

    f32x4 acc[4][8];
#pragma unroll
    for (int mi = 0; mi < 4; ++mi)
#pragma unroll
      for (int nj = 0; nj < 8; ++nj) acc[mi][nj] = (f32x4){0.f, 0.f, 0.f, 0.f};

    const unsigned short* bbase_g = cbt + ((size_t)f * IPAD + jbase) * KDIM;

    // preload kc=0 into registers (12 independent loads in flight)
#pragma unroll
    for (int p = 0; p < 4; ++p)
      rg[p] = *(const uint4*)(abase_g + (size_t)rA[p] * KDIM + sA[p] * 8);
#pragma unroll
    for (int p = 0; p < 8; ++p)
      rg[4 + p] = *(const uint4*)(bbase_g + (size_t)rB[p] * KDIM + sB[p] * 8);

    for (int kc = 0; kc < 8; ++kc) {
      __syncthreads();          // LDS A/B free (MFMA of kc-1 / scan done)
#pragma unroll
      for (int p = 0; p < 4; ++p)
        *(uint4*)((char*)Al + rA[p] * 144 + sA[p] * 16) = rg[p];
#pragma unroll
      for (int p = 0; p < 8; ++p)
        *(uint4*)((char*)Bl + rB[p] * 144 + sB[p] * 16) = rg[4 + p];
      __syncthreads();
      if (kc < 7) {             // prefetch kc+1 under the MFMAs
        const int c1 = (kc + 1) * 64;
#pragma unroll
        for (int p = 0; p < 4; ++p)
          rg[p] = *(const uint4*)(abase_g + (size_t)rA[p] * KDIM + c1 + sA[p] * 8);
#pragma unroll
        for (int p = 0; p < 8; ++p)
          rg[4 + p] = *(const uint4*)(bbase_g + (size_t)rB[p] * KDIM + c1 + sB[p] * 8);
      }
#pragma unroll
      for (int ks = 0; ks < 2; ++ks) {
        const int ka = ks * 32;
        bf16x8 a[4];
#pragma unroll
        for (int mi = 0; mi < 4; ++mi) a[mi] = *(const bf16x8*)(Al + aoff[mi] + ka);
#pragma unroll
        for (int nj = 0; nj < 8; ++nj) {
          bf16x8 b = *(const bf16x8*)(Bl + boff2[nj] + ka);
#pragma unroll
          for (int mi = 0; mi < 4; ++mi)
            acc[mi][nj] = __builtin_amdgcn_mfma_f32_16x16x32_bf16(a[mi], b, acc[mi][nj], 0, 0, 0);
        }
      }
    }

    // epilogue + scan: two phases of 128 j, all 256 threads scan
#pragma unroll
    for (int ph = 0; ph < 2; ++ph) {
      __syncthreads();
      if (wj == ph) {                          // these waves hold block-j [ph*128, +128)
#pragma unroll
        for (int mi = 0; mi < 4; ++mi) {
#pragma unroll
          for (int nj = 0; nj < 8; ++nj) {
#pragma unroll
            for (int r = 0; r < 4; ++r) {
              int row = wi * 64 + mi * 16 + lq * 4 + r;   // C: col=lane&15, row=quad*4+reg
              int col = nj * 16 + lrow;
              int q = col >> 2, rr = col & 3;
              Dl[row * 128 + (((q ^ (row & 7))) << 2) + rr] = acc[mi][nj][r];
            }
          }
        }
      }
      __syncthreads();
      if (rowok) {
        const int j0 = jbase + ph * 128 + half * 64;
        int cnt = F_TOT - j0; if (cnt > 64) cnt = 64;
        for (int bb = 0; bb < 16; ++bb) {
          const int bo = bb * 4;
          if (bo >= cnt) break;
          const int qq = half * 16 + bb;
          const float4 g4 = *(const float4*)&Dl[ii * 128 + ((qq ^ (ii & 7)) << 2)];
          const float4 s4 = *(const float4*)&sqj[ph * 128 + half * 64 + bo];
          float d0 = fmaxf(fmaf(-2.0f, g4.x, sqi + s4.x), 0.0f);
          float d1 = fmaxf(fmaf(-2.0f, g4.y, sqi + s4.y), 0.0f);
          float d2 = fmaxf(fmaf(-2.0f, g4.z, sqi + s4.z), 0.0f);
          float d3 = fmaxf(fmaf(-2.0f, g4.w, sqi + s4.w), 0.0f);
          const int rem = cnt - bo;
          if (rem < 4) d3 = __builtin_inff();
          if (rem < 3) d2 = __builtin_inff();
          if (rem < 2) d1 = __builtin_inff();
          float mn = fminf(fminf(d0, d1), fminf(d2, d3));
          if (mn <= bv[NCAND - 1]) {           // gate; exact lex insert inside
            float dd[4] = {d0, d1, d2, d3};
#pragma unroll
            for (int e = 0; e < 4; ++e) {      // ascending j within the quad
              float d = dd[e]; int jg = j0 + bo + e;
              if (d < bv[NCAND - 1] || (d == bv[NCAND - 1] && jg < bi[NCAND - 1])) {
                float cv = d; int ci = jg;
#pragma unroll
                for (int k = 0; k < NCAND; ++k) {
                  bool lt = (cv < bv[k]) || (cv == bv[k] && ci < bi[k]);
                  float tv = lt ? bv[k] : cv; int ti = lt ? bi[k] : ci;
                  bv[k] = lt ? cv : bv[k];    bi[k] = lt ? ci : bi[k];
                  cv = tv; ci = ti;
                }
              }
            }
          }
        }
      }
    }
  }

  // merge the two j-half partial top-10s (lex-exact == global top-10)
  __syncthreads();
  if (half == 1 && rowok) {
    float* wrow = &Dl[ii * 128];
#pragma unroll
    for (int k = 0; k < NCAND; ++k) { wrow[k] = bv[k]; *(int*)&wrow[NCAND + k] = bi[k]; }
  }
  __syncthreads();
  if (half == 0 && rowok) {
    const float* wrow = &Dl[ii * 128];
    float ov[NCAND]; int oi[NCAND];
#pragma unroll
    for (int k = 0; k < NCAND; ++k) { ov[k] = wrow[k]; oi[k] = *(const int*)&wrow[NCAND + k]; }
    float mv[NCAND]; int mj[NCAND];
    int p = 0, q = 0;
#pragma unroll
    for (int k = 0; k < NCAND; ++k) {          // two-pointer lex merge, pick 10 smallest
      bool mine = (q >= NCAND) || ((p < NCAND) &&
                  ((bv[p] < ov[q]) || (bv[p] == ov[q] && bi[p] < oi[q])));
      mv[k] = mine ? bv[p] : ov[q];
      mj[k] = mine ? bi[p] : oi[q];
      p += mine ? 1 : 0; q += mine ? 0 : 1;
    }
    (void)mv;
    // sort the 10 candidate j's ascending (odd-even transposition)
#pragma unroll
    for (int r = 0; r < NCAND; ++r) {
#pragma unroll
      for (int k = 0; k + 1 < NCAND; ++k) {
        if (((k ^ r) & 1) == 0) {
          int lo = min(mj[k], mj[k + 1]);
          int hi = max(mj[k], mj[k + 1]);
          mj[k] = lo; mj[k + 1] = hi;
        }
      }
    }
    int* dst = cand + ((size_t)(ibase + ii) * CF + f) * NCAND;
#pragma unroll
    for (int k = 0; k < NCAND; ++k) dst[k] = mj[k];
  }
}

// ------------------------------------------- k5: exact distances, 2 cands/thread
// VALIDATED round 3 arithmetic — ascending-c fmaf chain.
__global__ __launch_bounds__(256) void refine_dist_kernel(const float* __restrict__ ct,
                                                          const float* __restrict__ sq,
                                                          const int* __restrict__ cand,
                                                          float* __restrict__ dval) {
  int x = blockIdx.x * 256 + threadIdx.x;    // 0..159999
  if (x >= F_TOT * CF * (NCAND / 2)) return;
  int pf = x / (NCAND / 2);
  int m = x - pf * (NCAND / 2);
  int i = pf >> 4, f = pf & 15;
  const float* a = ct + ((size_t)f * F_TOT + i) * KDIM;
  float sqi = sq[i * CF + f];
  int j0 = cand[(size_t)pf * NCAND + 2 * m];
  int j1 = cand[(size_t)pf * NCAND + 2 * m + 1];
  const float* p = ct + ((size_t)f * F_TOT + j0) * KDIM;
  const float* q = ct + ((size_t)f * F_TOT + j1) * KDIM;
  float g0 = 0.0f, g1 = 0.0f;
  for (int c = 0; c < KDIM; c += 8) {
    float4 a0 = *(const float4*)(a + c), a1 = *(const float4*)(a + c + 4);
    float4 p0 = *(const float4*)(p + c), p1 = *(const float4*)(p + c + 4);
    float4 q0 = *(const float4*)(q + c), q1 = *(const float4*)(q + c + 4);
    g0 = fmaf(a0.x, p0.x, g0); g1 = fmaf(a0.x, q0.x, g1);
    g0 = fmaf(a0.y, p0.y, g0); g1 = fmaf(a0.y, q0.y, g1);
    g0 = fmaf(a0.z, p0.z, g0); g1 = fmaf(a0.z, q0.z, g1);
    g0 = fmaf(a0.w, p0.w, g0); g1 = fmaf(a0.w, q0.w, g1);
    g0 = fmaf(a1.x, p1.x, g0); g1 = fmaf(a1.x, q1.x, g1);
    g0 = fmaf(a1.y, p1.y, g0); g1 = fmaf(a1.y, q1.y, g1);
    g0 = fmaf(a1.z, p1.z, g0); g1 = fmaf(a1.z, q1.z, g1);
    g0 = fmaf(a1.w, p1.w, g0); g1 = fmaf(a1.w, q1.w, g1);
  }
  float d0 = fmaf(-2.0f, g0, sqi + sq[j0 * CF + f]); d0 = fmaxf(d0, 0.0f);
  float d1 = fmaf(-2.0f, g1, sqi + sq[j1 * CF + f]); d1 = fmaxf(d1, 0.0f);
  dval[(size_t)pf * NCAND + 2 * m]     = d0;
  dval[(size_t)pf * NCAND + 2 * m + 1] = d1;
}

// ------------------------------------------- k6: top-8 select (ascending-j, strict <)
__global__ __launch_bounds__(256) void select_kernel(const float* __restrict__ dval,
                                                     const int* __restrict__ cand,
                                                     int* __restrict__ fidx) {
  int pf = blockIdx.x * 256 + threadIdx.x;   // (i*16+f), 0..31999
  if (pf >= F_TOT * CF) return;
  int i = pf >> 4, f = pf & 15;
  float bval[NB_K]; int bidx[NB_K];
#pragma unroll
  for (int k = 0; k < NB_K; ++k) { bval[k] = __builtin_inff(); bidx[k] = 0; }
#pragma unroll
  for (int m = 0; m < NCAND; ++m) {          // ascending j (cand sorted)
    float d = dval[(size_t)pf * NCAND + m];
    int j = cand[(size_t)pf * NCAND + m];
    if (d < bval[NB_K - 1]) {
      float cv = d; int ci = j;
#pragma unroll
      for (int k = 0; k < NB_K; ++k)
        if (cv < bval[k]) {
          float tv = bval[k]; bval[k] = cv; cv = tv;
          int ti = bidx[k]; bidx[k] = ci; ci = ti;
        }
    }
  }
#pragma unroll
  for (int k = 0; k < NB_K; ++k)
    fidx[((size_t)i * NB_K + k) * CF + f] = bidx[k];
}

// ---------------------------------------------------------------- k7: gather
__global__ __launch_bounds__(256) void gather_kernel(const float* __restrict__ inputs,
                                                     const int* __restrict__ fidx,
                                                     float* __restrict__ out) {
  int b = blockIdx.y;
  int x = blockIdx.x * 256 + threadIdx.x;    // m*16+c
  int c = x & 15;
  int n = fidx[x];
  out[(size_t)b * (F_TOT * NB_K * CF) + x] =
      inputs[(size_t)b * (F_TOT * CF) + n * CF + c];
}

// ---------------------------------------------------------------- launcher
extern "C" void kernel_launch(void* const* d_in, const int* in_sizes, int n_in,
                              void* d_out, int out_size, void* d_ws, size_t ws_size,
                              hipStream_t stream) {
  const float* inputs = (const float*)d_in[0];   // (64, 2000, 16)
  const float* coords = (const float*)d_in[1];   // (512, 2000, 16)
  float* out = (float*)d_out;

  unsigned short* cbt = (unsigned short*)d_out;  // 16*2048*512 bf16 (phase 1)
  float* ct = (float*)d_out;                     // 16*2000*512 f32 (phase 2, == out_size)

  float* sq = (float*)d_ws;                      // 32768 floats
  int* cand = (int*)d_ws + 32768;                // 32000*10 ints
  float* dval = (float*)d_ws + 32768 + 32000 * NCAND; // 32000*10 floats
  int* fidx = (int*)d_ws + 32768 + 2 * 32000 * NCAND; // 256000 ints

  sq_kernel<<<F_TOT, 256, 0, stream>>>(coords, sq);
  cvt_bf16_kernel<<<dim3(IPAD / 16, KDIM / 32), 256, 0, stream>>>(coords, cbt);
  approx_kernel<<<256, 256, 0, stream>>>(cbt, sq, cand);
  cvt_f32t_kernel<<<dim3(F_TOT / 16, KDIM / 32), 256, 0, stream>>>(coords, ct);
  refine_dist_kernel<<<(F_TOT * CF * (NCAND / 2) + 255) / 256, 256, 0, stream>>>(ct, sq, cand, dval);
  select_kernel<<<(F_TOT * CF + 255) / 256, 256, 0, stream>>>(dval, cand, fidx);
  dim3 g7((F_TOT * NB_K * CF) / 256, 64);
  gather_kernel<<<g7, 256, 0, stream>>>(inputs, fidx, out);
}

// Round 5
// 937.804 us; speedup vs baseline: 1.1619x; 1.1619x over previous
//
#include <hip/hip_runtime.h>
#include <math.h>

// PhyloNeighbours: per-filter (16) kNN (k=8) over 2000 features, 512-dim coords.
// v5: approx kernel — grid 512 (j split in 2 chunks of 1000 -> 2 blocks/CU),
// batched load->ds_write staging (temps die before MFMA; v4's cross-barrier
// register prefetch spilled: VGPR 240, 313MB scratch writes), unpadded
// XOR-swizzled LDS (seg ^ (row&7)) for conflict-free b128 everywhere.
// Candidates: top-10 per chunk (superset of v3's global top-10). Refine/select
// consume 20 ascending-j candidates with the validated exact arithmetic.
//
// Memory plan:
//   d_out: phase 1 holds cbt[f][2048][512] bf16 (32 MB); phase 2 holds
//          ct[f][2000][512] fp32 (exactly out_size floats); final gather output.
//   d_ws : sq 128KB + cand 2.56MB + dval 2.56MB + fidx 1MB ~= 6.3 MB.

#define F_TOT 2000
#define CF    16
#define KDIM  512
#define NB_K  8
#define IPAD  2048
#define NCAND 10
#define NCH   2
#define NCTOT (NCAND * NCH)

typedef __attribute__((ext_vector_type(8))) short bf16x8;
typedef __attribute__((ext_vector_type(4))) float f32x4;

__device__ inline unsigned short f2bf(float x) {
  unsigned int u = __float_as_uint(x);
  return (unsigned short)((u + 0x7fffu + ((u >> 16) & 1u)) >> 16);
}

// ---------------------------------------------------------------- k1: sq (fp64)
// VALIDATED rounds 1-4 — do not change arithmetic.
__global__ __launch_bounds__(256) void sq_kernel(const float* __restrict__ coords,
                                                 float* __restrict__ sq_out) {
  int i = blockIdx.x;
  int t = threadIdx.x;
  int f = t & 15;
  int cg = t >> 4;
  const float* base = coords + (size_t)i * CF + f;
  double s = 0.0;
  for (int c = cg * 32; c < cg * 32 + 32; ++c) {
    float v = base[(size_t)c * (F_TOT * CF)];
    s += (double)v * (double)v;
  }
  __shared__ double red[256];
  red[t] = s;
  __syncthreads();
  if (cg == 0) {
    double tot = 0.0;
#pragma unroll
    for (int g = 0; g < 16; ++g) tot += red[g * 16 + f];
    sq_out[i * CF + f] = (float)tot;
  }
}

// ------------------------------------------- k2: coords -> cbt[f][i pad2048][c] bf16
__global__ __launch_bounds__(256) void cvt_bf16_kernel(const float* __restrict__ coords,
                                                       unsigned short* __restrict__ cbt) {
  __shared__ float lds[32 * 257];
  const int i0 = blockIdx.x * 16;    // 0..2032
  const int c0 = blockIdx.y * 32;
  const int t = threadIdx.x;
  const int io = t >> 4, f = t & 15;
  const int iclamp = min(i0 + io, F_TOT - 1);
  for (int cc = 0; cc < 32; ++cc)
    lds[cc * 257 + t] = coords[(size_t)(c0 + cc) * (F_TOT * CF) + iclamp * CF + f];
  __syncthreads();
  size_t obase = ((size_t)f * IPAD + (i0 + io)) * KDIM + c0;
#pragma unroll
  for (int cc = 0; cc < 32; cc += 4) {
    unsigned int lo = (unsigned int)f2bf(lds[(cc + 0) * 257 + t]) |
                      ((unsigned int)f2bf(lds[(cc + 1) * 257 + t]) << 16);
    unsigned int hi = (unsigned int)f2bf(lds[(cc + 2) * 257 + t]) |
                      ((unsigned int)f2bf(lds[(cc + 3) * 257 + t]) << 16);
    *(uint2*)(cbt + obase + cc) = make_uint2(lo, hi);
  }
}

// ------------------------------------------- k4: coords -> ct[f][i 2000][c] fp32
__global__ __launch_bounds__(256) void cvt_f32t_kernel(const float* __restrict__ coords,
                                                       float* __restrict__ ct) {
  __shared__ float lds[32 * 257];
  const int i0 = blockIdx.x * 16;    // 0..1984 (125 tiles exact)
  const int c0 = blockIdx.y * 32;
  const int t = threadIdx.x;
  const int io = t >> 4;
  for (int cc = 0; cc < 32; ++cc)
    lds[cc * 257 + t] = coords[(size_t)(c0 + cc) * (F_TOT * CF) + i0 * CF + t];
  __syncthreads();
  const int f = t & 15;
  size_t obase = ((size_t)f * F_TOT + (i0 + io)) * KDIM + c0;
#pragma unroll
  for (int cc = 0; cc < 32; cc += 4) {
    float4 v = make_float4(lds[(cc + 0) * 257 + t], lds[(cc + 1) * 257 + t],
                           lds[(cc + 2) * 257 + t], lds[(cc + 3) * 257 + t]);
    *(float4*)(ct + obase + cc) = v;
  }
}

// ------------------------------------------- k3: bf16 MFMA approx + top-10/chunk
// grid 512: f = bx&15, i-tile(128) = (bx>>4)&15, j-chunk(1000) = bx>>8.
// Staging: batched 12 uint4 loads then 12 ds_writes (temps dead before MFMA).
// LDS: unpadded 128B rows, physical seg = seg ^ (row&7) (<=2-way, free).
// Scan: 256 threads, thread pair (ii, ii+128) splits each row's 128-j phase;
// partial top-10s merged lex-exact (validated v4 logic).
__global__ __launch_bounds__(256, 2) void approx_kernel(const unsigned short* __restrict__ cbt,
                                                        const float* __restrict__ sq,
                                                        int* __restrict__ cand) {
  const int bx = blockIdx.x;
  const int f = bx & 15;
  const int it = (bx >> 4) & 15;
  const int jc = bx >> 8;
  const int ibase = it * 128;
  const int jcbase = jc * 1000;
  const int jlimit = jcbase + 1000;

  const int t = threadIdx.x;
  const int lane = t & 63;
  const int w = t >> 6;
  const int wi = w & 1, wj = w >> 1;
  const int lrow = lane & 15, lq = lane >> 4;

  __shared__ char smem[66560];
  unsigned short* Al = (unsigned short*)smem;             // [128][64] bf16, 128B rows
  unsigned short* Bl = (unsigned short*)(smem + 16384);   // [256][64] bf16
  float* Dl = (float*)smem;                               // [128][128] f32 swizzled (alias)
  float* sqj = (float*)(smem + 65536);                    // [256]

  const unsigned short* abase_g = cbt + ((size_t)f * IPAD + ibase) * KDIM;

  // scan identity: row ii, j-half (64 j per 128-j phase)
  const int ii = t & 127;
  const int half = t >> 7;
  const bool rowok = (ibase + ii < F_TOT);

  float bv[NCAND]; int bi[NCAND];
#pragma unroll
  for (int k = 0; k < NCAND; ++k) { bv[k] = __builtin_inff(); bi[k] = 0x7fffffff; }
  float sqi = rowok ? sq[(ibase + ii) * CF + f] : 0.0f;

  // A-fragment row geometry (per mi)
  int arow[4];
#pragma unroll
  for (int mi = 0; mi < 4; ++mi) arow[mi] = wi * 64 + mi * 16 + lrow;
  int brow[8];
#pragma unroll
  for (int nj = 0; nj < 8; ++nj) brow[nj] = wj * 128 + nj * 16 + lrow;

  for (int js = 0; js < 4; ++js) {
    const int jbase = jcbase + js * 256;
    __syncthreads();   // previous js's scan (Dl/sqj readers) done
    { int jg = jbase + t; sqj[t] = (jg < F_TOT) ? sq[jg * CF + f] : 0.0f; }

    f32x4 acc[4][8];
#pragma unroll
    for (int mi = 0; mi < 4; ++mi)
#pragma unroll
      for (int nj = 0; nj < 8; ++nj) acc[mi][nj] = (f32x4){0.f, 0.f, 0.f, 0.f};

    const unsigned short* bbase_g = cbt + ((size_t)f * IPAD + jbase) * KDIM;

    for (int kc = 0; kc < 8; ++kc) {
      const int c0 = kc * 64;
      __syncthreads();          // LDS A/B free (MFMA of kc-1 / scan done)
      {
        uint4 tmp[12];
#pragma unroll
        for (int p = 0; p < 4; ++p) {          // batch-issue all 12 loads
          int slot = t + p * 256, r = slot >> 3, sg = slot & 7;
          tmp[p] = *(const uint4*)(abase_g + (size_t)r * KDIM + c0 + sg * 8);
        }
#pragma unroll
        for (int p = 0; p < 8; ++p) {
          int slot = t + p * 256, r = slot >> 3, sg = slot & 7;
          tmp[4 + p] = *(const uint4*)(bbase_g + (size_t)r * KDIM + c0 + sg * 8);
        }
#pragma unroll
        for (int p = 0; p < 4; ++p) {          // then commit (XOR-swizzled seg)
          int slot = t + p * 256, r = slot >> 3, sg = slot & 7;
          *(uint4*)((char*)Al + r * 128 + ((sg ^ (r & 7)) << 4)) = tmp[p];
        }
#pragma unroll
        for (int p = 0; p < 8; ++p) {
          int slot = t + p * 256, r = slot >> 3, sg = slot & 7;
          *(uint4*)((char*)Bl + r * 128 + ((sg ^ (r & 7)) << 4)) = tmp[4 + p];
        }
      }
      __syncthreads();
#pragma unroll
      for (int ks = 0; ks < 2; ++ks) {
        bf16x8 a[4];
#pragma unroll
        for (int mi = 0; mi < 4; ++mi) {
          int sg = ks * 4 + lq;
          a[mi] = *(const bf16x8*)(Al + arow[mi] * 64 + ((sg ^ (arow[mi] & 7)) << 3));
        }
#pragma unroll
        for (int nj = 0; nj < 8; ++nj) {
          int sg = ks * 4 + lq;
          bf16x8 b = *(const bf16x8*)(Bl + brow[nj] * 64 + ((sg ^ (brow[nj] & 7)) << 3));
#pragma unroll
          for (int mi = 0; mi < 4; ++mi)
            acc[mi][nj] = __builtin_amdgcn_mfma_f32_16x16x32_bf16(a[mi], b, acc[mi][nj], 0, 0, 0);
        }
      }
    }

    // epilogue + scan: two phases of 128 j, all 256 threads scan
#pragma unroll
    for (int ph = 0; ph < 2; ++ph) {
      __syncthreads();
      if (wj == ph) {                          // these waves hold block-j [ph*128, +128)
#pragma unroll
        for (int mi = 0; mi < 4; ++mi) {
#pragma unroll
          for (int nj = 0; nj < 8; ++nj) {
#pragma unroll
            for (int r = 0; r < 4; ++r) {
              int row = wi * 64 + mi * 16 + lq * 4 + r;   // C: col=lane&15, row=quad*4+reg
              int col = nj * 16 + lrow;
              int q = col >> 2, rr = col & 3;
              Dl[row * 128 + (((q ^ (row & 7))) << 2) + rr] = acc[mi][nj][r];
            }
          }
        }
      }
      __syncthreads();
      if (rowok) {
        const int j0 = jbase + ph * 128 + half * 64;
        int cnt = jlimit - j0; if (cnt > 64) cnt = 64;
        for (int bb = 0; bb < 16; ++bb) {
          const int bo = bb * 4;
          if (bo >= cnt) break;
          const int qq = half * 16 + bb;
          const float4 g4 = *(const float4*)&Dl[ii * 128 + ((qq ^ (ii & 7)) << 2)];
          const float4 s4 = *(const float4*)&sqj[ph * 128 + half * 64 + bo];
          float d0 = fmaxf(fmaf(-2.0f, g4.x, sqi + s4.x), 0.0f);
          float d1 = fmaxf(fmaf(-2.0f, g4.y, sqi + s4.y), 0.0f);
          float d2 = fmaxf(fmaf(-2.0f, g4.z, sqi + s4.z), 0.0f);
          float d3 = fmaxf(fmaf(-2.0f, g4.w, sqi + s4.w), 0.0f);
          const int rem = cnt - bo;
          if (rem < 4) d3 = __builtin_inff();
          if (rem < 3) d2 = __builtin_inff();
          if (rem < 2) d1 = __builtin_inff();
          float mn = fminf(fminf(d0, d1), fminf(d2, d3));
          if (mn <= bv[NCAND - 1]) {           // gate; exact lex insert inside
            float dd[4] = {d0, d1, d2, d3};
#pragma unroll
            for (int e = 0; e < 4; ++e) {      // ascending j within the quad
              float d = dd[e]; int jg = j0 + bo + e;
              if (d < bv[NCAND - 1] || (d == bv[NCAND - 1] && jg < bi[NCAND - 1])) {
                float cv = d; int ci = jg;
#pragma unroll
                for (int k = 0; k < NCAND; ++k) {
                  bool lt = (cv < bv[k]) || (cv == bv[k] && ci < bi[k]);
                  float tv = lt ? bv[k] : cv; int ti = lt ? bi[k] : ci;
                  bv[k] = lt ? cv : bv[k];    bi[k] = lt ? ci : bi[k];
                  cv = tv; ci = ti;
                }
              }
            }
          }
        }
      }
    }
  }

  // merge the two j-half partial top-10s (lex-exact == chunk top-10)
  __syncthreads();
  if (half == 1 && rowok) {
    float* wrow = &Dl[ii * 128];
#pragma unroll
    for (int k = 0; k < NCAND; ++k) { wrow[k] = bv[k]; *(int*)&wrow[NCAND + k] = bi[k]; }
  }
  __syncthreads();
  if (half == 0 && rowok) {
    const float* wrow = &Dl[ii * 128];
    float ov[NCAND]; int oi[NCAND];
#pragma unroll
    for (int k = 0; k < NCAND; ++k) { ov[k] = wrow[k]; oi[k] = *(const int*)&wrow[NCAND + k]; }
    float mv[NCAND]; int mj[NCAND];
    int p = 0, q = 0;
#pragma unroll
    for (int k = 0; k < NCAND; ++k) {          // two-pointer lex merge, pick 10 smallest
      bool mine = (q >= NCAND) || ((p < NCAND) &&
                  ((bv[p] < ov[q]) || (bv[p] == ov[q] && bi[p] < oi[q])));
      mv[k] = mine ? bv[p] : ov[q];
      mj[k] = mine ? bi[p] : oi[q];
      p += mine ? 1 : 0; q += mine ? 0 : 1;
    }
    (void)mv;
    // sort the 10 candidate j's ascending (odd-even transposition)
#pragma unroll
    for (int r = 0; r < NCAND; ++r) {
#pragma unroll
      for (int k = 0; k + 1 < NCAND; ++k) {
        if (((k ^ r) & 1) == 0) {
          int lo = min(mj[k], mj[k + 1]);
          int hi = max(mj[k], mj[k + 1]);
          mj[k] = lo; mj[k + 1] = hi;
        }
      }
    }
    int* dst = cand + ((size_t)(ibase + ii) * CF + f) * NCTOT + jc * NCAND;
#pragma unroll
    for (int k = 0; k < NCAND; ++k) dst[k] = mj[k];
  }
}

// ------------------------------------------- k5: exact distances, 2 cands/thread
// VALIDATED arithmetic — ascending-c fmaf chain. 20 cands -> 10 pairs per (i,f).
__global__ __launch_bounds__(256) void refine_dist_kernel(const float* __restrict__ ct,
                                                          const float* __restrict__ sq,
                                                          const int* __restrict__ cand,
                                                          float* __restrict__ dval) {
  int x = blockIdx.x * 256 + threadIdx.x;    // 0..319999
  if (x >= F_TOT * CF * (NCTOT / 2)) return;
  int pf = x / (NCTOT / 2);
  int m = x - pf * (NCTOT / 2);
  int i = pf >> 4, f = pf & 15;
  const float* a = ct + ((size_t)f * F_TOT + i) * KDIM;
  float sqi = sq[i * CF + f];
  int j0 = cand[(size_t)pf * NCTOT + 2 * m];
  int j1 = cand[(size_t)pf * NCTOT + 2 * m + 1];
  const float* p = ct + ((size_t)f * F_TOT + j0) * KDIM;
  const float* q = ct + ((size_t)f * F_TOT + j1) * KDIM;
  float g0 = 0.0f, g1 = 0.0f;
  for (int c = 0; c < KDIM; c += 8) {
    float4 a0 = *(const float4*)(a + c), a1 = *(const float4*)(a + c + 4);
    float4 p0 = *(const float4*)(p + c), p1 = *(const float4*)(p + c + 4);
    float4 q0 = *(const float4*)(q + c), q1 = *(const float4*)(q + c + 4);
    g0 = fmaf(a0.x, p0.x, g0); g1 = fmaf(a0.x, q0.x, g1);
    g0 = fmaf(a0.y, p0.y, g0); g1 = fmaf(a0.y, q0.y, g1);
    g0 = fmaf(a0.z, p0.z, g0); g1 = fmaf(a0.z, q0.z, g1);
    g0 = fmaf(a0.w, p0.w, g0); g1 = fmaf(a0.w, q0.w, g1);
    g0 = fmaf(a1.x, p1.x, g0); g1 = fmaf(a1.x, q1.x, g1);
    g0 = fmaf(a1.y, p1.y, g0); g1 = fmaf(a1.y, q1.y, g1);
    g0 = fmaf(a1.z, p1.z, g0); g1 = fmaf(a1.z, q1.z, g1);
    g0 = fmaf(a1.w, p1.w, g0); g1 = fmaf(a1.w, q1.w, g1);
  }
  float d0 = fmaf(-2.0f, g0, sqi + sq[j0 * CF + f]); d0 = fmaxf(d0, 0.0f);
  float d1 = fmaf(-2.0f, g1, sqi + sq[j1 * CF + f]); d1 = fmaxf(d1, 0.0f);
  dval[(size_t)pf * NCTOT + 2 * m]     = d0;
  dval[(size_t)pf * NCTOT + 2 * m + 1] = d1;
}

// ------------------------------------------- k6: top-8 select (ascending-j, strict <)
__global__ __launch_bounds__(256) void select_kernel(const float* __restrict__ dval,
                                                     const int* __restrict__ cand,
                                                     int* __restrict__ fidx) {
  int pf = blockIdx.x * 256 + threadIdx.x;   // (i*16+f), 0..31999
  if (pf >= F_TOT * CF) return;
  int i = pf >> 4, f = pf & 15;
  float bval[NB_K]; int bidx[NB_K];
#pragma unroll
  for (int k = 0; k < NB_K; ++k) { bval[k] = __builtin_inff(); bidx[k] = 0; }
#pragma unroll
  for (int m = 0; m < NCTOT; ++m) {          // ascending j (chunks disjoint ascending)
    float d = dval[(size_t)pf * NCTOT + m];
    int j = cand[(size_t)pf * NCTOT + m];
    if (d < bval[NB_K - 1]) {
      float cv = d; int ci = j;
#pragma unroll
      for (int k = 0; k < NB_K; ++k)
        if (cv < bval[k]) {
          float tv = bval[k]; bval[k] = cv; cv = tv;
          int ti = bidx[k]; bidx[k] = ci; ci = ti;
        }
    }
  }
#pragma unroll
  for (int k = 0; k < NB_K; ++k)
    fidx[((size_t)i * NB_K + k) * CF + f] = bidx[k];
}

// ---------------------------------------------------------------- k7: gather
__global__ __launch_bounds__(256) void gather_kernel(const float* __restrict__ inputs,
                                                     const int* __restrict__ fidx,
                                                     float* __restrict__ out) {
  int b = blockIdx.y;
  int x = blockIdx.x * 256 + threadIdx.x;    // m*16+c
  int c = x & 15;
  int n = fidx[x];
  out[(size_t)b * (F_TOT * NB_K * CF) + x] =
      inputs[(size_t)b * (F_TOT * CF) + n * CF + c];
}

// ---------------------------------------------------------------- launcher
extern "C" void kernel_launch(void* const* d_in, const int* in_sizes, int n_in,
                              void* d_out, int out_size, void* d_ws, size_t ws_size,
                              hipStream_t stream) {
  const float* inputs = (const float*)d_in[0];   // (64, 2000, 16)
  const float* coords = (const float*)d_in[1];   // (512, 2000, 16)
  float* out = (float*)d_out;

  unsigned short* cbt = (unsigned short*)d_out;  // 16*2048*512 bf16 (phase 1)
  float* ct = (float*)d_out;                     // 16*2000*512 f32 (phase 2, == out_size)

  float* sq = (float*)d_ws;                      // 32768 floats
  int* cand = (int*)d_ws + 32768;                // 32000*20 ints
  float* dval = (float*)d_ws + 32768 + 32000 * NCTOT; // 32000*20 floats
  int* fidx = (int*)d_ws + 32768 + 2 * 32000 * NCTOT; // 256000 ints

  sq_kernel<<<F_TOT, 256, 0, stream>>>(coords, sq);
  cvt_bf16_kernel<<<dim3(IPAD / 16, KDIM / 32), 256, 0, stream>>>(coords, cbt);
  approx_kernel<<<512, 256, 0, stream>>>(cbt, sq, cand);
  cvt_f32t_kernel<<<dim3(F_TOT / 16, KDIM / 32), 256, 0, stream>>>(coords, ct);
  refine_dist_kernel<<<(F_TOT * CF * (NCTOT / 2) + 255) / 256, 256, 0, stream>>>(ct, sq, cand, dval);
  select_kernel<<<(F_TOT * CF + 255) / 256, 256, 0, stream>>>(dval, cand, fidx);
  dim3 g7((F_TOT * NB_K * CF) / 256, 64);
  gather_kernel<<<g7, 256, 0, stream>>>(inputs, fidx, out);
}